// Round 1
// baseline (3362.670 us; speedup 1.0000x reference)
//
#include <hip/hip_runtime.h>

#ifndef NUM_NODES_C
#define NUM_NODES_C 100000
#endif

// Kernel 1: histogram of tokens per node.
__global__ void asl_count_kernel(const int* __restrict__ map,
                                 unsigned int* __restrict__ cnt, int n) {
    int i = blockIdx.x * blockDim.x + threadIdx.x;
    int stride = gridDim.x * blockDim.x;
    for (; i < n; i += stride) {
        atomicAdd(&cnt[map[i]], 1u);
    }
}

// Kernel 2: inv[i] = count ? 1/count : 0
__global__ void asl_inv_kernel(const unsigned int* __restrict__ cnt,
                               float* __restrict__ inv, int n) {
    int i = blockIdx.x * blockDim.x + threadIdx.x;
    if (i < n) {
        unsigned int c = cnt[i];
        inv[i] = c ? (1.0f / (float)c) : 0.0f;
    }
}

// Kernel 3: out[node] += data[token] * inv[node]
// Thread layout: tid>>6 = token, tid&63 = float4-chunk within the 256-float row.
// A full wave (64 lanes) = one token -> map/inv loads are wave-uniform
// (broadcast), data row load is one fully-coalesced 1KB vector read.
__global__ void asl_scatter_kernel(const float4* __restrict__ data,
                                   const int* __restrict__ map,
                                   const float* __restrict__ inv,
                                   float* __restrict__ out, int n_tokens) {
    long long tid = (long long)blockIdx.x * blockDim.x + threadIdx.x;
    int token = (int)(tid >> 6);
    if (token >= n_tokens) return;
    int chunk = (int)(tid & 63);

    int node = map[token];            // wave-uniform
    float w = inv[node];              // wave-uniform

    float4 v = data[(size_t)token * 64 + chunk];
    float* o = out + (size_t)node * 256 + (size_t)chunk * 4;
    // HW fp32 atomics (global_atomic_add_f32), no CAS loop.
    unsafeAtomicAdd(o + 0, v.x * w);
    unsafeAtomicAdd(o + 1, v.y * w);
    unsafeAtomicAdd(o + 2, v.z * w);
    unsafeAtomicAdd(o + 3, v.w * w);
}

extern "C" void kernel_launch(void* const* d_in, const int* in_sizes, int n_in,
                              void* d_out, int out_size, void* d_ws, size_t ws_size,
                              hipStream_t stream) {
    const float* data = (const float*)d_in[0];       // (N, 256) fp32
    const int*   map  = (const int*)d_in[1];         // (N,) int
    // d_in[2..4] = W, b, scoring -> dead code in the reference, unused.

    const int n_tokens = in_sizes[1];                // N = 1,000,000
    float* out = (float*)d_out;                      // (NUM_NODES, 256) fp32

    unsigned int* cnt = (unsigned int*)d_ws;                         // 400 KB
    float*        inv = (float*)((char*)d_ws + NUM_NODES_C * 4);     // 400 KB

    // Harness poisons d_out/d_ws once and never re-poisons between replays:
    // zero both accumulators every call (async memset = graph-capturable).
    hipMemsetAsync(out, 0, (size_t)out_size * sizeof(float), stream);
    hipMemsetAsync(cnt, 0, (size_t)NUM_NODES_C * sizeof(unsigned int), stream);

    {
        int block = 256;
        int grid = (n_tokens + block - 1) / block;
        asl_count_kernel<<<grid, block, 0, stream>>>(map, cnt, n_tokens);
    }
    {
        int block = 256;
        int grid = (NUM_NODES_C + block - 1) / block;
        asl_inv_kernel<<<grid, block, 0, stream>>>(cnt, inv, NUM_NODES_C);
    }
    {
        int block = 256;
        long long total = (long long)n_tokens * 64;  // 64 float4 chunks per token
        int grid = (int)((total + block - 1) / block);
        asl_scatter_kernel<<<grid, block, 0, stream>>>(
            (const float4*)data, map, inv, out, n_tokens);
    }
}

// Round 2
// 580.814 us; speedup vs baseline: 5.7896x; 5.7896x over previous
//
#include <hip/hip_runtime.h>

#ifndef NUM_NODES_C
#define NUM_NODES_C 100000
#endif

// ---------- Kernel 1: histogram of tokens per node ----------
__global__ void asl_count_kernel(const int* __restrict__ map,
                                 unsigned int* __restrict__ cnt, int n) {
    int i = blockIdx.x * blockDim.x + threadIdx.x;
    int stride = gridDim.x * blockDim.x;
    for (; i < n; i += stride) {
        atomicAdd(&cnt[map[i]], 1u);
    }
}

// ---------- Kernel 2: single-block exclusive scan over cnt ----------
// base[i] = exclusive prefix sum; next[i] = copy of base[i] (fill cursor).
// 1024 threads, each owns a contiguous chunk; Hillis-Steele scan of the
// 1024 per-thread sums in LDS.
__global__ __launch_bounds__(1024)
void asl_scan_kernel(const unsigned int* __restrict__ cnt,
                     unsigned int* __restrict__ base,
                     unsigned int* __restrict__ next, int n) {
    __shared__ unsigned int part[1024];
    int t = threadIdx.x;
    int chunk = (n + 1023) / 1024;
    int lo = t * chunk;
    int hi = min(lo + chunk, n);

    unsigned int s = 0;
    for (int i = lo; i < hi; ++i) s += cnt[i];
    part[t] = s;
    __syncthreads();

    // inclusive scan of part[]
    for (int off = 1; off < 1024; off <<= 1) {
        unsigned int v = (t >= off) ? part[t - off] : 0u;
        __syncthreads();
        part[t] += v;
        __syncthreads();
    }
    unsigned int running = (t == 0) ? 0u : part[t - 1];  // exclusive offset

    for (int i = lo; i < hi; ++i) {
        base[i] = running;
        next[i] = running;
        running += cnt[i];
    }
}

// ---------- Kernel 3: fill CSR token lists ----------
__global__ void asl_fill_kernel(const int* __restrict__ map,
                                unsigned int* __restrict__ next,
                                int* __restrict__ list, int n) {
    int i = blockIdx.x * blockDim.x + threadIdx.x;
    int stride = gridDim.x * blockDim.x;
    for (; i < n; i += stride) {
        unsigned int pos = atomicAdd(&next[map[i]], 1u);
        list[pos] = i;
    }
}

// ---------- Kernel 4: gather-mean, one wave per node ----------
// lane l owns float4 chunk l of the 256-float row (64*16B = 1KB, coalesced).
// No atomics: each output row written exactly once (zeros for empty nodes).
__global__ void asl_gather_kernel(const float4* __restrict__ data,
                                  const int* __restrict__ list,
                                  const unsigned int* __restrict__ base,
                                  const unsigned int* __restrict__ cnt,
                                  float4* __restrict__ out, int num_nodes) {
    long long tid = (long long)blockIdx.x * blockDim.x + threadIdx.x;
    int node = (int)(tid >> 6);
    if (node >= num_nodes) return;
    int lane = (int)(tid & 63);

    unsigned int b = base[node];   // wave-uniform
    unsigned int c = cnt[node];    // wave-uniform

    float4 acc = make_float4(0.f, 0.f, 0.f, 0.f);
    unsigned int j = 0;
    // unroll-by-2 for a little ILP on the dependent list->data chain
    for (; j + 2 <= c; j += 2) {
        int t0 = list[b + j];
        int t1 = list[b + j + 1];
        float4 v0 = data[(size_t)t0 * 64 + lane];
        float4 v1 = data[(size_t)t1 * 64 + lane];
        acc.x += v0.x + v1.x;
        acc.y += v0.y + v1.y;
        acc.z += v0.z + v1.z;
        acc.w += v0.w + v1.w;
    }
    if (j < c) {
        int t0 = list[b + j];
        float4 v0 = data[(size_t)t0 * 64 + lane];
        acc.x += v0.x; acc.y += v0.y; acc.z += v0.z; acc.w += v0.w;
    }

    float w = c ? (1.0f / (float)c) : 0.0f;
    acc.x *= w; acc.y *= w; acc.z *= w; acc.w *= w;
    out[(size_t)node * 64 + lane] = acc;
}

extern "C" void kernel_launch(void* const* d_in, const int* in_sizes, int n_in,
                              void* d_out, int out_size, void* d_ws, size_t ws_size,
                              hipStream_t stream) {
    const float* data = (const float*)d_in[0];   // (N, 256) fp32
    const int*   map  = (const int*)d_in[1];     // (N,) int
    // d_in[2..4] = W, b, scoring -> dead code in the reference, unused.

    const int n_tokens = in_sizes[1];            // N = 1,000,000
    float* out = (float*)d_out;                  // (NUM_NODES, 256) fp32

    // workspace layout
    unsigned int* cnt  = (unsigned int*)d_ws;                              // 400 KB
    unsigned int* base = (unsigned int*)((char*)d_ws + 1 * NUM_NODES_C*4); // 400 KB
    unsigned int* next = (unsigned int*)((char*)d_ws + 2 * NUM_NODES_C*4); // 400 KB
    int*          list = (int*)        ((char*)d_ws + 3 * NUM_NODES_C*4);  // 4 MB

    hipMemsetAsync(cnt, 0, (size_t)NUM_NODES_C * sizeof(unsigned int), stream);

    {
        int block = 256;
        int grid = (n_tokens + block - 1) / block;
        asl_count_kernel<<<grid, block, 0, stream>>>(map, cnt, n_tokens);
    }
    asl_scan_kernel<<<1, 1024, 0, stream>>>(cnt, base, next, NUM_NODES_C);
    {
        int block = 256;
        int grid = (n_tokens + block - 1) / block;
        asl_fill_kernel<<<grid, block, 0, stream>>>(map, next, list, n_tokens);
    }
    {
        int block = 256;                                  // 4 waves/block
        long long total = (long long)NUM_NODES_C * 64;    // one wave per node
        int grid = (int)((total + block - 1) / block);
        asl_gather_kernel<<<grid, block, 0, stream>>>(
            (const float4*)data, list, base, cnt, (float4*)out, NUM_NODES_C);
    }
}

// Round 3
// 572.936 us; speedup vs baseline: 5.8692x; 1.0137x over previous
//
#include <hip/hip_runtime.h>

#ifndef NUM_NODES_C
#define NUM_NODES_C 100000
#endif

// ---------- Kernel 1: histogram of tokens per node ----------
__global__ void asl_count_kernel(const int* __restrict__ map,
                                 unsigned int* __restrict__ cnt, int n) {
    int i = blockIdx.x * blockDim.x + threadIdx.x;
    int stride = gridDim.x * blockDim.x;
    for (; i < n; i += stride) {
        atomicAdd(&cnt[map[i]], 1u);
    }
}

// ---------- Kernel 2: single-block exclusive scan over cnt ----------
__global__ __launch_bounds__(1024)
void asl_scan_kernel(const unsigned int* __restrict__ cnt,
                     unsigned int* __restrict__ base,
                     unsigned int* __restrict__ next, int n) {
    __shared__ unsigned int part[1024];
    int t = threadIdx.x;
    int chunk = (n + 1023) / 1024;
    int lo = t * chunk;
    int hi = min(lo + chunk, n);

    unsigned int s = 0;
    for (int i = lo; i < hi; ++i) s += cnt[i];
    part[t] = s;
    __syncthreads();

    for (int off = 1; off < 1024; off <<= 1) {
        unsigned int v = (t >= off) ? part[t - off] : 0u;
        __syncthreads();
        part[t] += v;
        __syncthreads();
    }
    unsigned int running = (t == 0) ? 0u : part[t - 1];  // exclusive offset

    for (int i = lo; i < hi; ++i) {
        base[i] = running;
        next[i] = running;
        running += cnt[i];
    }
}

// ---------- Kernel 3: fill CSR token lists ----------
__global__ void asl_fill_kernel(const int* __restrict__ map,
                                unsigned int* __restrict__ next,
                                int* __restrict__ list, int n) {
    int i = blockIdx.x * blockDim.x + threadIdx.x;
    int stride = gridDim.x * blockDim.x;
    for (; i < n; i += stride) {
        unsigned int pos = atomicAdd(&next[map[i]], 1u);
        list[pos] = i;
    }
}

// ---------- Kernel 4: gather-mean, one wave per node ----------
// lane l owns float4 chunk l of the 256-float row (64*16B = 1KB per row read,
// fully coalesced). Token indices are prefetched 64-at-a-time coalesced into
// lanes and broadcast via __shfl, so row loads have NO serial dependency:
// unroll x4 + 2 accumulators keeps 4 independent 1KB loads in flight/wave.
__global__ void asl_gather_kernel(const float4* __restrict__ data,
                                  const int* __restrict__ list,
                                  const unsigned int* __restrict__ base,
                                  const unsigned int* __restrict__ cnt,
                                  float4* __restrict__ out, int num_nodes) {
    long long tid = (long long)blockIdx.x * blockDim.x + threadIdx.x;
    int node = (int)(tid >> 6);
    if (node >= num_nodes) return;
    int lane = (int)(tid & 63);

    unsigned int b = base[node];   // wave-uniform
    unsigned int c = cnt[node];    // wave-uniform

    float4 a0 = make_float4(0.f, 0.f, 0.f, 0.f);
    float4 a1 = make_float4(0.f, 0.f, 0.f, 0.f);

    for (unsigned int j0 = 0; j0 < c; j0 += 64) {
        unsigned int rem = min(64u, c - j0);
        // coalesced prefetch of the next <=64 token indices into lanes
        int tl = (lane < (int)rem) ? list[b + j0 + lane] : 0;

        unsigned int j = 0;
        for (; j + 4 <= rem; j += 4) {
            int t0 = __shfl(tl, (int)j);
            int t1 = __shfl(tl, (int)j + 1);
            int t2 = __shfl(tl, (int)j + 2);
            int t3 = __shfl(tl, (int)j + 3);
            float4 v0 = data[(size_t)t0 * 64 + lane];
            float4 v1 = data[(size_t)t1 * 64 + lane];
            float4 v2 = data[(size_t)t2 * 64 + lane];
            float4 v3 = data[(size_t)t3 * 64 + lane];
            a0.x += v0.x; a0.y += v0.y; a0.z += v0.z; a0.w += v0.w;
            a1.x += v1.x; a1.y += v1.y; a1.z += v1.z; a1.w += v1.w;
            a0.x += v2.x; a0.y += v2.y; a0.z += v2.z; a0.w += v2.w;
            a1.x += v3.x; a1.y += v3.y; a1.z += v3.z; a1.w += v3.w;
        }
        for (; j < rem; ++j) {
            int t0 = __shfl(tl, (int)j);
            float4 v0 = data[(size_t)t0 * 64 + lane];
            a0.x += v0.x; a0.y += v0.y; a0.z += v0.z; a0.w += v0.w;
        }
    }

    float w = c ? (1.0f / (float)c) : 0.0f;
    float4 r;
    r.x = (a0.x + a1.x) * w;
    r.y = (a0.y + a1.y) * w;
    r.z = (a0.z + a1.z) * w;
    r.w = (a0.w + a1.w) * w;
    out[(size_t)node * 64 + lane] = r;
}

extern "C" void kernel_launch(void* const* d_in, const int* in_sizes, int n_in,
                              void* d_out, int out_size, void* d_ws, size_t ws_size,
                              hipStream_t stream) {
    const float* data = (const float*)d_in[0];   // (N, 256) fp32
    const int*   map  = (const int*)d_in[1];     // (N,) int
    // d_in[2..4] = W, b, scoring -> dead code in the reference, unused.

    const int n_tokens = in_sizes[1];            // N = 1,000,000
    float* out = (float*)d_out;                  // (NUM_NODES, 256) fp32

    // workspace layout
    unsigned int* cnt  = (unsigned int*)d_ws;                              // 400 KB
    unsigned int* base = (unsigned int*)((char*)d_ws + 1 * NUM_NODES_C*4); // 400 KB
    unsigned int* next = (unsigned int*)((char*)d_ws + 2 * NUM_NODES_C*4); // 400 KB
    int*          list = (int*)        ((char*)d_ws + 3 * NUM_NODES_C*4);  // 4 MB

    hipMemsetAsync(cnt, 0, (size_t)NUM_NODES_C * sizeof(unsigned int), stream);

    {
        int block = 256;
        int grid = (n_tokens + block - 1) / block;
        asl_count_kernel<<<grid, block, 0, stream>>>(map, cnt, n_tokens);
    }
    asl_scan_kernel<<<1, 1024, 0, stream>>>(cnt, base, next, NUM_NODES_C);
    {
        int block = 256;
        int grid = (n_tokens + block - 1) / block;
        asl_fill_kernel<<<grid, block, 0, stream>>>(map, next, list, n_tokens);
    }
    {
        int block = 256;                                  // 4 waves/block
        long long total = (long long)NUM_NODES_C * 64;    // one wave per node
        int grid = (int)((total + block - 1) / block);
        asl_gather_kernel<<<grid, block, 0, stream>>>(
            (const float4*)data, list, base, cnt, (float4*)out, NUM_NODES_C);
    }
}

// Round 4
// 344.116 us; speedup vs baseline: 9.7719x; 1.6649x over previous
//
#include <hip/hip_runtime.h>

#define NN 100000            // NUM_NODES
#define TILE 256
#define NB ((NN + TILE - 1) / TILE)   // 391 tiles

typedef float floatx4 __attribute__((ext_vector_type(4)));

// ---------- Kernel 1: histogram of tokens per node ----------
__global__ void asl_count_kernel(const int* __restrict__ map,
                                 unsigned int* __restrict__ cnt, int n) {
    int i = blockIdx.x * blockDim.x + threadIdx.x;
    int stride = gridDim.x * blockDim.x;
    for (; i < n; i += stride) {
        atomicAdd(&cnt[map[i]], 1u);
    }
}

// ---------- Scan pass A: per-tile sums (coalesced) ----------
__global__ void asl_blocksum_kernel(const unsigned int* __restrict__ cnt,
                                    unsigned int* __restrict__ blocksum) {
    __shared__ unsigned int sh[TILE];
    int t = threadIdx.x, b = blockIdx.x;
    int i = b * TILE + t;
    unsigned int v = (i < NN) ? cnt[i] : 0u;
    sh[t] = v;
    __syncthreads();
    for (int off = TILE / 2; off > 0; off >>= 1) {
        if (t < off) sh[t] += sh[t + off];
        __syncthreads();
    }
    if (t == 0) blocksum[b] = sh[0];
}

// ---------- Scan pass B: exclusive scan of 391 tile sums (1 block) ----------
__global__ __launch_bounds__(512)
void asl_scanblocks_kernel(const unsigned int* __restrict__ blocksum,
                           unsigned int* __restrict__ blockoff) {
    __shared__ unsigned int sh[512];
    int t = threadIdx.x;
    unsigned int v = (t < NB) ? blocksum[t] : 0u;
    sh[t] = v;
    __syncthreads();
    for (int off = 1; off < 512; off <<= 1) {
        unsigned int y = (t >= off) ? sh[t - off] : 0u;
        __syncthreads();
        sh[t] += y;
        __syncthreads();
    }
    if (t < NB) blockoff[t] = sh[t] - v;   // exclusive
}

// ---------- Scan pass C: per-tile exclusive scan + offset (coalesced) ----------
__global__ void asl_scantiles_kernel(const unsigned int* __restrict__ cnt,
                                     const unsigned int* __restrict__ blockoff,
                                     unsigned int* __restrict__ base,
                                     unsigned int* __restrict__ next) {
    __shared__ unsigned int sh[TILE];
    int t = threadIdx.x, b = blockIdx.x;
    int i = b * TILE + t;
    unsigned int v = (i < NN) ? cnt[i] : 0u;
    sh[t] = v;
    __syncthreads();
    for (int off = 1; off < TILE; off <<= 1) {
        unsigned int y = (t >= off) ? sh[t - off] : 0u;
        __syncthreads();
        sh[t] += y;
        __syncthreads();
    }
    unsigned int excl = sh[t] - v + blockoff[b];
    if (i < NN) {
        base[i] = excl;
        next[i] = excl;
    }
}

// ---------- Kernel: fill CSR token lists ----------
__global__ void asl_fill_kernel(const int* __restrict__ map,
                                unsigned int* __restrict__ next,
                                int* __restrict__ list, int n) {
    int i = blockIdx.x * blockDim.x + threadIdx.x;
    int stride = gridDim.x * blockDim.x;
    for (; i < n; i += stride) {
        unsigned int pos = atomicAdd(&next[map[i]], 1u);
        list[pos] = i;
    }
}

// ---------- Gather-mean: one wave per node ----------
// lane l owns float4 chunk l of the 256-float row (64*16B = 1KB per row,
// fully coalesced). Token indices prefetched 64-at-a-time coalesced into
// lanes, broadcast via __shfl; unroll x4 keeps 4 independent row loads in
// flight. data loads / out stores are nontemporal (read/write-once) so the
// CSR metadata stays cache-resident.
__global__ void asl_gather_kernel(const floatx4* __restrict__ data,
                                  const int* __restrict__ list,
                                  const unsigned int* __restrict__ base,
                                  const unsigned int* __restrict__ cnt,
                                  floatx4* __restrict__ out, int num_nodes) {
    long long tid = (long long)blockIdx.x * blockDim.x + threadIdx.x;
    int node = (int)(tid >> 6);
    if (node >= num_nodes) return;
    int lane = (int)(tid & 63);

    unsigned int b = base[node];   // wave-uniform
    unsigned int c = cnt[node];    // wave-uniform

    floatx4 a0 = {0.f, 0.f, 0.f, 0.f};
    floatx4 a1 = {0.f, 0.f, 0.f, 0.f};

    for (unsigned int j0 = 0; j0 < c; j0 += 64) {
        unsigned int rem = min(64u, c - j0);
        int tl = (lane < (int)rem) ? list[b + j0 + lane] : 0;

        unsigned int j = 0;
        for (; j + 4 <= rem; j += 4) {
            int t0 = __shfl(tl, (int)j);
            int t1 = __shfl(tl, (int)j + 1);
            int t2 = __shfl(tl, (int)j + 2);
            int t3 = __shfl(tl, (int)j + 3);
            floatx4 v0 = __builtin_nontemporal_load(&data[(size_t)t0 * 64 + lane]);
            floatx4 v1 = __builtin_nontemporal_load(&data[(size_t)t1 * 64 + lane]);
            floatx4 v2 = __builtin_nontemporal_load(&data[(size_t)t2 * 64 + lane]);
            floatx4 v3 = __builtin_nontemporal_load(&data[(size_t)t3 * 64 + lane]);
            a0 += v0; a1 += v1; a0 += v2; a1 += v3;
        }
        for (; j < rem; ++j) {
            int t0 = __shfl(tl, (int)j);
            a0 += __builtin_nontemporal_load(&data[(size_t)t0 * 64 + lane]);
        }
    }

    float w = c ? (1.0f / (float)c) : 0.0f;
    floatx4 r = (a0 + a1) * w;
    __builtin_nontemporal_store(r, &out[(size_t)node * 64 + lane]);
}

extern "C" void kernel_launch(void* const* d_in, const int* in_sizes, int n_in,
                              void* d_out, int out_size, void* d_ws, size_t ws_size,
                              hipStream_t stream) {
    const float* data = (const float*)d_in[0];   // (N, 256) fp32
    const int*   map  = (const int*)d_in[1];     // (N,) int
    // d_in[2..4] = W, b, scoring -> dead code in the reference, unused.

    const int n_tokens = in_sizes[1];            // N = 1,000,000
    float* out = (float*)d_out;                  // (NN, 256) fp32

    // workspace layout (u32 units)
    unsigned int* ws       = (unsigned int*)d_ws;
    unsigned int* cnt      = ws;                  // NN
    unsigned int* base     = ws + NN;             // NN
    unsigned int* next     = ws + 2 * NN;         // NN
    int*          list     = (int*)(ws + 3 * NN); // n_tokens
    unsigned int* blocksum = ws + 3 * NN + n_tokens;        // NB
    unsigned int* blockoff = ws + 3 * NN + n_tokens + NB;   // NB

    hipMemsetAsync(cnt, 0, (size_t)NN * sizeof(unsigned int), stream);

    {
        int block = 256;
        int grid = (n_tokens + block - 1) / block;
        asl_count_kernel<<<grid, block, 0, stream>>>(map, cnt, n_tokens);
    }
    asl_blocksum_kernel<<<NB, TILE, 0, stream>>>(cnt, blocksum);
    asl_scanblocks_kernel<<<1, 512, 0, stream>>>(blocksum, blockoff);
    asl_scantiles_kernel<<<NB, TILE, 0, stream>>>(cnt, blockoff, base, next);
    {
        int block = 256;
        int grid = (n_tokens + block - 1) / block;
        asl_fill_kernel<<<grid, block, 0, stream>>>(map, next, list, n_tokens);
    }
    {
        int block = 256;                                  // 4 waves/block
        long long total = (long long)NN * 64;             // one wave per node
        int grid = (int)((total + block - 1) / block);
        asl_gather_kernel<<<grid, block, 0, stream>>>(
            (const floatx4*)data, list, base, cnt, (floatx4*)out, NN);
    }
}

// Round 5
// 326.222 us; speedup vs baseline: 10.3079x; 1.0549x over previous
//
#include <hip/hip_runtime.h>

#define NN 100000                 // NUM_NODES
#define STILE 512
#define SNB ((NN + STILE - 1) / STILE)   // 196 scan tiles (< 512, fits one block-scan)

typedef float floatx4 __attribute__((ext_vector_type(4)));
typedef int   intx4   __attribute__((ext_vector_type(4)));

// ---------- Kernel 1: histogram of tokens per node (int4 map reads) ----------
__global__ void asl_count_kernel(const intx4* __restrict__ map4,
                                 const int* __restrict__ map,
                                 unsigned int* __restrict__ cnt, int n) {
    int n4 = n >> 2;
    int i = blockIdx.x * blockDim.x + threadIdx.x;
    int stride = gridDim.x * blockDim.x;
    for (; i < n4; i += stride) {
        intx4 m = map4[i];
        atomicAdd(&cnt[m.x], 1u);
        atomicAdd(&cnt[m.y], 1u);
        atomicAdd(&cnt[m.z], 1u);
        atomicAdd(&cnt[m.w], 1u);
    }
    if (blockIdx.x == 0 && threadIdx.x < (n & 3)) {
        atomicAdd(&cnt[map[(n4 << 2) + threadIdx.x]], 1u);
    }
}

// ---------- Scan pass A: per-tile sums (coalesced, 512-wide) ----------
__global__ __launch_bounds__(STILE)
void asl_blocksum_kernel(const unsigned int* __restrict__ cnt,
                         unsigned int* __restrict__ blocksum) {
    __shared__ unsigned int sh[STILE];
    int t = threadIdx.x, b = blockIdx.x;
    int i = b * STILE + t;
    sh[t] = (i < NN) ? cnt[i] : 0u;
    __syncthreads();
    for (int off = STILE / 2; off > 0; off >>= 1) {
        if (t < off) sh[t] += sh[t + off];
        __syncthreads();
    }
    if (t == 0) blocksum[b] = sh[0];
}

// ---------- Scan pass B+C fused: each block inline-scans the 196 tile sums,
// then scans its own 512-tile and writes base/next. base has NN+1 entries. ----------
__global__ __launch_bounds__(STILE)
void asl_scantiles_kernel(const unsigned int* __restrict__ cnt,
                          const unsigned int* __restrict__ blocksum,
                          unsigned int* __restrict__ base,
                          unsigned int* __restrict__ next) {
    __shared__ unsigned int sh[STILE];
    int t = threadIdx.x, b = blockIdx.x;

    // inclusive scan of blocksum[0..SNB) (padded with zeros to 512)
    sh[t] = (t < SNB) ? blocksum[t] : 0u;
    __syncthreads();
    for (int off = 1; off < STILE; off <<= 1) {
        unsigned int y = (t >= off) ? sh[t - off] : 0u;
        __syncthreads();
        sh[t] += y;
        __syncthreads();
    }
    unsigned int blockoff = (b == 0) ? 0u : sh[b - 1];  // exclusive offset (LDS broadcast)
    __syncthreads();                                    // before reusing sh

    int i = b * STILE + t;
    unsigned int v = (i < NN) ? cnt[i] : 0u;
    sh[t] = v;
    __syncthreads();
    for (int off = 1; off < STILE; off <<= 1) {
        unsigned int y = (t >= off) ? sh[t - off] : 0u;
        __syncthreads();
        sh[t] += y;
        __syncthreads();
    }
    unsigned int excl = blockoff + sh[t] - v;
    if (i < NN) {
        base[i] = excl;
        next[i] = excl;
        if (i == NN - 1) base[NN] = excl + v;   // grand total
    }
}

// ---------- Fill CSR token lists (int4 map reads) ----------
__global__ void asl_fill_kernel(const intx4* __restrict__ map4,
                                const int* __restrict__ map,
                                unsigned int* __restrict__ next,
                                int* __restrict__ list, int n) {
    int n4 = n >> 2;
    int i = blockIdx.x * blockDim.x + threadIdx.x;
    int stride = gridDim.x * blockDim.x;
    for (; i < n4; i += stride) {
        intx4 m = map4[i];
        int tok = i << 2;
        list[atomicAdd(&next[m.x], 1u)] = tok;
        list[atomicAdd(&next[m.y], 1u)] = tok + 1;
        list[atomicAdd(&next[m.z], 1u)] = tok + 2;
        list[atomicAdd(&next[m.w], 1u)] = tok + 3;
    }
    if (blockIdx.x == 0 && threadIdx.x < (n & 3)) {
        int tok = (n4 << 2) + threadIdx.x;
        list[atomicAdd(&next[map[tok]], 1u)] = tok;
    }
}

// ---------- Gather-mean: one wave per node ----------
// lane l owns float4 chunk l of the 256-float row (64x16B = 1KB/row, coalesced).
// Token indices prefetched 64-at-a-time coalesced into lanes, broadcast via
// __shfl; unroll x8 with 4 accumulators keeps 8 independent 1KB row loads in
// flight per wave. data/list/out are nontemporal (streaming, read/write-once).
__global__ void asl_gather_kernel(const floatx4* __restrict__ data,
                                  const int* __restrict__ list,
                                  const unsigned int* __restrict__ base,
                                  floatx4* __restrict__ out, int num_nodes) {
    long long tid = (long long)blockIdx.x * blockDim.x + threadIdx.x;
    int node = (int)(tid >> 6);
    if (node >= num_nodes) return;
    int lane = (int)(tid & 63);

    unsigned int b = base[node];         // wave-uniform
    unsigned int c = base[node + 1] - b; // wave-uniform

    floatx4 a0 = {0.f,0.f,0.f,0.f}, a1 = {0.f,0.f,0.f,0.f};
    floatx4 a2 = {0.f,0.f,0.f,0.f}, a3 = {0.f,0.f,0.f,0.f};

    for (unsigned int j0 = 0; j0 < c; j0 += 64) {
        unsigned int rem = min(64u, c - j0);
        int tl = (lane < (int)rem) ? __builtin_nontemporal_load(&list[b + j0 + lane]) : 0;

        unsigned int j = 0;
        for (; j + 8 <= rem; j += 8) {
            int t0 = __shfl(tl, (int)j);
            int t1 = __shfl(tl, (int)j + 1);
            int t2 = __shfl(tl, (int)j + 2);
            int t3 = __shfl(tl, (int)j + 3);
            int t4 = __shfl(tl, (int)j + 4);
            int t5 = __shfl(tl, (int)j + 5);
            int t6 = __shfl(tl, (int)j + 6);
            int t7 = __shfl(tl, (int)j + 7);
            floatx4 v0 = __builtin_nontemporal_load(&data[(size_t)t0 * 64 + lane]);
            floatx4 v1 = __builtin_nontemporal_load(&data[(size_t)t1 * 64 + lane]);
            floatx4 v2 = __builtin_nontemporal_load(&data[(size_t)t2 * 64 + lane]);
            floatx4 v3 = __builtin_nontemporal_load(&data[(size_t)t3 * 64 + lane]);
            floatx4 v4 = __builtin_nontemporal_load(&data[(size_t)t4 * 64 + lane]);
            floatx4 v5 = __builtin_nontemporal_load(&data[(size_t)t5 * 64 + lane]);
            floatx4 v6 = __builtin_nontemporal_load(&data[(size_t)t6 * 64 + lane]);
            floatx4 v7 = __builtin_nontemporal_load(&data[(size_t)t7 * 64 + lane]);
            a0 += v0; a1 += v1; a2 += v2; a3 += v3;
            a0 += v4; a1 += v5; a2 += v6; a3 += v7;
        }
        for (; j + 4 <= rem; j += 4) {
            int t0 = __shfl(tl, (int)j);
            int t1 = __shfl(tl, (int)j + 1);
            int t2 = __shfl(tl, (int)j + 2);
            int t3 = __shfl(tl, (int)j + 3);
            a0 += __builtin_nontemporal_load(&data[(size_t)t0 * 64 + lane]);
            a1 += __builtin_nontemporal_load(&data[(size_t)t1 * 64 + lane]);
            a2 += __builtin_nontemporal_load(&data[(size_t)t2 * 64 + lane]);
            a3 += __builtin_nontemporal_load(&data[(size_t)t3 * 64 + lane]);
        }
        for (; j < rem; ++j) {
            int t0 = __shfl(tl, (int)j);
            a0 += __builtin_nontemporal_load(&data[(size_t)t0 * 64 + lane]);
        }
    }

    float w = c ? (1.0f / (float)c) : 0.0f;
    floatx4 r = ((a0 + a1) + (a2 + a3)) * w;
    __builtin_nontemporal_store(r, &out[(size_t)node * 64 + lane]);
}

extern "C" void kernel_launch(void* const* d_in, const int* in_sizes, int n_in,
                              void* d_out, int out_size, void* d_ws, size_t ws_size,
                              hipStream_t stream) {
    const float* data = (const float*)d_in[0];   // (N, 256) fp32
    const int*   map  = (const int*)d_in[1];     // (N,) int
    // d_in[2..4] = W, b, scoring -> dead code in the reference, unused.

    const int n_tokens = in_sizes[1];            // N = 1,000,000
    float* out = (float*)d_out;                  // (NN, 256) fp32

    // workspace layout (u32 units)
    unsigned int* ws       = (unsigned int*)d_ws;
    unsigned int* cnt      = ws;                        // NN
    unsigned int* base     = ws + NN;                   // NN + 1
    unsigned int* next     = ws + 2 * NN + 1;           // NN
    int*          list     = (int*)(ws + 3 * NN + 1);   // n_tokens
    unsigned int* blocksum = ws + 3 * NN + 1 + n_tokens; // SNB

    hipMemsetAsync(cnt, 0, (size_t)NN * sizeof(unsigned int), stream);

    {
        int block = 256;
        int grid = ((n_tokens >> 2) + block - 1) / block;
        asl_count_kernel<<<grid, block, 0, stream>>>(
            (const intx4*)map, map, cnt, n_tokens);
    }
    asl_blocksum_kernel<<<SNB, STILE, 0, stream>>>(cnt, blocksum);
    asl_scantiles_kernel<<<SNB, STILE, 0, stream>>>(cnt, blocksum, base, next);
    {
        int block = 256;
        int grid = ((n_tokens >> 2) + block - 1) / block;
        asl_fill_kernel<<<grid, block, 0, stream>>>(
            (const intx4*)map, map, next, list, n_tokens);
    }
    {
        int block = 256;                                  // 4 waves/block
        long long total = (long long)NN * 64;             // one wave per node
        int grid = (int)((total + block - 1) / block);
        asl_gather_kernel<<<grid, block, 0, stream>>>(
            (const floatx4*)data, list, base, (floatx4*)out, NN);
    }
}